// Round 1
// baseline (457.245 us; speedup 1.0000x reference)
//
#include <hip/hip_runtime.h>

// SCF GRU layer: T=40 steps, B=128 batches, N=64 agents/batch, H=48 hidden.
// BN = 8192 rows. DIN = 52 = loc(2) + rel(2) + vel(16) + img_feat(32).
//
// Decomposition (2 launches):
//  k_pre : blocks [0,4096)    -> img_feat[b][c] = mean over 80x80 of f_img (HBM-bound, 105 MB)
//          blocks [4096,5376) -> S[t][b][2] = sum of locs over the 64 agents (4 (t,b) per block)
//  k_gru : per-row independent 40-step recurrence. 96 threads/row:
//          thread = (gate j in [0,48), half in {0,1} of K-range).
//          G0 (time-invariant img part of gi) computed in the prologue per block.
//          Weights (102 floats/thread) live in REGISTERS -- __launch_bounds__(192,3)
//          gives the allocator ~170 VGPRs so they are NOT spilled per step.
//          h and x double-buffered in LDS -> ONE barrier per step.
//          Global loads for step t+1 prefetched into registers before the barrier.

#define T_STEPS 40
#define BB      128
#define NN      64
#define HH      48
#define BN      8192
#define G3      144   // 3*H

__device__ __forceinline__ float sigmoid_(float x) {
    return __builtin_amdgcn_rcpf(1.0f + __expf(-x));
}

__global__ __launch_bounds__(256) void k_pre(const float* __restrict__ f_img,
                                             const float* __restrict__ path,
                                             float* __restrict__ img_out,
                                             float* __restrict__ S) {
    if (blockIdx.x < 4096) {
        // ---- per-(b,c) image mean over 80x80 = 1600 float4 ----
        const int bc = blockIdx.x;
        const float4* p = reinterpret_cast<const float4*>(f_img + (size_t)bc * 6400);
        float s = 0.0f;
        for (int i = threadIdx.x; i < 1600; i += 256) {
            float4 v = p[i];
            s += v.x + v.y + v.z + v.w;
        }
        for (int off = 32; off > 0; off >>= 1) s += __shfl_down(s, off, 64);
        __shared__ float red[4];
        const int wid = threadIdx.x >> 6, lane = threadIdx.x & 63;
        if (lane == 0) red[wid] = s;
        __syncthreads();
        if (threadIdx.x == 0)
            img_out[bc] = (red[0] + red[1] + red[2] + red[3]) * (1.0f / 6400.0f);
    } else {
        // ---- loc sums: one (t,b) per wave, 4 waves/block ----
        const int tb   = (blockIdx.x - 4096) * 4 + (threadIdx.x >> 6);  // t*128 + b
        const int lane = threadIdx.x & 63;
        const float2 v = reinterpret_cast<const float2*>(path)[(size_t)tb * 64 + lane];
        float sx = v.x, sy = v.y;
        for (int off = 32; off > 0; off >>= 1) {
            sx += __shfl_down(sx, off, 64);
            sy += __shfl_down(sy, off, 64);
        }
        if (lane == 0) {
            float2 o; o.x = sx; o.y = sy;
            reinterpret_cast<float2*>(S)[tb] = o;
        }
    }
}

// Main recurrence. Block = 192 threads = 2 rows x 96 threads.
// Within a row: lane q = j*2 + half, so shfl_xor(1) pairs the two K-halves.
// __launch_bounds__(192,3): 3 waves/EU -> VGPR cap ~170 so the 102 weight
// floats per thread stay register-resident (84-VGPR default spilled them).
__global__ __launch_bounds__(192, 3) void k_gru(const float* __restrict__ path,
                                                const float* __restrict__ f_vel,
                                                const float* __restrict__ W_ih,
                                                const float* __restrict__ W_hh,
                                                const float* __restrict__ b_ih,
                                                const float* __restrict__ b_hh,
                                                const float* __restrict__ img,
                                                const float* __restrict__ S,
                                                float* __restrict__ out) {
    const int tid  = threadIdx.x;
    const int r    = tid / 96;       // row slot within block
    const int q    = tid % 96;
    const int j    = q >> 1;         // gate/hidden index 0..47
    const int half = q & 1;          // K-range half
    const int row  = blockIdx.x * 2 + r;
    const int b    = row >> 6;       // batch = row / 64  (both rows same batch)

    __shared__ float sh[2][2][HH];   // [buf][row][j]  hidden state, double-buffered
    __shared__ float sx[2][2][20];   // [buf][row][.]  time-varying input, double-buffered
    __shared__ float g0sh[G3];       // per-batch time-invariant gi part

    // ---- G0 prologue: g0[g] = b_ih[g] + img_feat[b] . W_ih[g, 20:52] ----
    if (tid < G3) {
        float acc = b_ih[tid];
        const float* w  = W_ih + tid * 52 + 20;
        const float* im = img + b * 32;
#pragma unroll
        for (int c = 0; c < 32; ++c) acc = fmaf(im[c], w[c], acc);
        g0sh[tid] = acc;
    }

    // ---- weights into registers (float2 pairs) ----
    float2 wihr[5], wihz[5], wihn[5];      // x-part, K-half = 10 floats each gate
    float2 whhr[12], whhz[12], whhn[12];   // h-part, K-half = 24 floats each gate
    {
        const float2* wr = reinterpret_cast<const float2*>(W_ih + (j)      * 52 + half * 10);
        const float2* wz = reinterpret_cast<const float2*>(W_ih + (48 + j) * 52 + half * 10);
        const float2* wn = reinterpret_cast<const float2*>(W_ih + (96 + j) * 52 + half * 10);
#pragma unroll
        for (int p = 0; p < 5; ++p) { wihr[p] = wr[p]; wihz[p] = wz[p]; wihn[p] = wn[p]; }
    }
    {
        const float2* wr = reinterpret_cast<const float2*>(W_hh + (j)      * 48 + half * 24);
        const float2* wz = reinterpret_cast<const float2*>(W_hh + (48 + j) * 48 + half * 24);
        const float2* wn = reinterpret_cast<const float2*>(W_hh + (96 + j) * 48 + half * 24);
#pragma unroll
        for (int p = 0; p < 12; ++p) { whhr[p] = wr[p]; whhz[p] = wz[p]; whhn[p] = wn[p]; }
    }
    const float bhr = b_hh[j], bhz = b_hh[48 + j], bhn = b_hh[96 + j];

    if (half == 0) sh[0][r][j] = 0.0f;   // h0 = 0

    // ---- prefetch step-0 inputs into registers ----
    float  vcur = 0.0f, vnxt = 0.0f;
    float2 lcur = {0.f, 0.f}, lnxt = {0.f, 0.f};
    float2 scur = {0.f, 0.f}, snxt = {0.f, 0.f};
    if (q < 16) {
        vcur = f_vel[(size_t)row * 16 + q];
    } else if (q == 16) {
        lcur = reinterpret_cast<const float2*>(path)[row];
        scur = reinterpret_cast<const float2*>(S)[b];
    }

    __syncthreads();   // g0sh + sh[0] ready
    const float g0r = g0sh[j], g0z = g0sh[48 + j], g0n = g0sh[96 + j];

    float hp = 0.0f;   // h_prev for this j, carried in a register (both halves identical)
    int p = 0;
    for (int t = 0; t < T_STEPS; ++t) {
        // ---- stage x[t] (held in regs) into LDS buffer p ----
        if (q < 16) {
            sx[p][r][4 + q] = vcur;
        } else if (q == 16) {
            sx[p][r][0] = lcur.x;
            sx[p][r][1] = lcur.y;
            sx[p][r][2] = (scur.x - 64.0f * lcur.x) * (1.0f / 63.0f);  // rel = (S-64*loc)/63
            sx[p][r][3] = (scur.y - 64.0f * lcur.y) * (1.0f / 63.0f);
        }
        // ---- prefetch t+1 (latency hides under this step's compute) ----
        if (t + 1 < T_STEPS) {
            if (q < 16) {
                vnxt = f_vel[((size_t)(t + 1) * BN + row) * 16 + q];
            } else if (q == 16) {
                lnxt = reinterpret_cast<const float2*>(path)[(size_t)(t + 1) * BN + row];
                snxt = reinterpret_cast<const float2*>(S)[(t + 1) * BB + b];
            }
        }
        __syncthreads();   // sx[p] staged, sh[p] (written last step) visible

        const float2* sx2 = reinterpret_cast<const float2*>(sx[p][r]);
        const float2* sh2 = reinterpret_cast<const float2*>(sh[p][r]);

        float2 ar  = {0.0f, 0.0f};   // r-gate: i + h combined
        float2 az  = {0.0f, 0.0f};   // z-gate: i + h combined
        float2 ani = {0.0f, 0.0f};   // n-gate input part
        float2 anh = {0.0f, 0.0f};   // n-gate hidden part (r multiplies this)
#pragma unroll
        for (int pp = 0; pp < 5; ++pp) {
            const float2 xv = sx2[half * 5 + pp];
            ar.x  = fmaf(xv.x, wihr[pp].x, ar.x);  ar.y  = fmaf(xv.y, wihr[pp].y, ar.y);
            az.x  = fmaf(xv.x, wihz[pp].x, az.x);  az.y  = fmaf(xv.y, wihz[pp].y, az.y);
            ani.x = fmaf(xv.x, wihn[pp].x, ani.x); ani.y = fmaf(xv.y, wihn[pp].y, ani.y);
        }
#pragma unroll
        for (int pp = 0; pp < 12; ++pp) {
            const float2 hv = sh2[half * 12 + pp];
            ar.x  = fmaf(hv.x, whhr[pp].x, ar.x);  ar.y  = fmaf(hv.y, whhr[pp].y, ar.y);
            az.x  = fmaf(hv.x, whhz[pp].x, az.x);  az.y  = fmaf(hv.y, whhz[pp].y, az.y);
            anh.x = fmaf(hv.x, whhn[pp].x, anh.x); anh.y = fmaf(hv.y, whhn[pp].y, anh.y);
        }
        float sr  = ar.x + ar.y;   sr  += __shfl_xor(sr, 1, 64);
        float szv = az.x + az.y;   szv += __shfl_xor(szv, 1, 64);
        float sni = ani.x + ani.y; sni += __shfl_xor(sni, 1, 64);
        float snh = anh.x + anh.y; snh += __shfl_xor(snh, 1, 64);

        const float rg = sigmoid_(sr + g0r + bhr);
        const float zg = sigmoid_(szv + g0z + bhz);
        float a = (sni + g0n) + rg * (snh + bhn);   // b_hh inside r*h_n (not folded into G0)
        a = fminf(fmaxf(a, -15.0f), 15.0f);
        const float e = __expf(-2.0f * a);
        const float cand = (1.0f - e) * __builtin_amdgcn_rcpf(1.0f + e);
        const float hn = zg * (hp - cand) + cand;   // (1-z)*cand + z*h

        // write to the OTHER buffer -> no pre-write barrier needed
        if (half == 0) {
            sh[p ^ 1][r][j] = hn;
        } else {
            out[((size_t)t * BN + row) * HH + j] = hn;
            if (t == T_STEPS - 1)
                out[(size_t)T_STEPS * BN * HH + (size_t)row * HH + j] = hn;  // hT
        }
        hp = hn;
        vcur = vnxt; lcur = lnxt; scur = snxt;
        p ^= 1;
    }
}

extern "C" void kernel_launch(void* const* d_in, const int* in_sizes, int n_in,
                              void* d_out, int out_size, void* d_ws, size_t ws_size,
                              hipStream_t stream) {
    const float* path  = (const float*)d_in[0];
    const float* f_vel = (const float*)d_in[1];
    const float* f_img = (const float*)d_in[2];
    const float* W_ih  = (const float*)d_in[3];
    const float* W_hh  = (const float*)d_in[4];
    const float* b_ih  = (const float*)d_in[5];
    const float* b_hh  = (const float*)d_in[6];
    float* out = (float*)d_out;

    float* ws  = (float*)d_ws;
    float* img = ws;                  // 4096 floats
    float* S   = ws + 4096;           // 10240 floats (float2-aligned: 16 KB offset)

    // img_mean blocks [0,4096) + ssum blocks [4096, 4096+1280)
    hipLaunchKernelGGL(k_pre, dim3(4096 + (T_STEPS * BB) / 4), dim3(256), 0, stream,
                       f_img, path, img, S);
    hipLaunchKernelGGL(k_gru, dim3(BN / 2), dim3(192), 0, stream,
                       path, f_vel, W_ih, W_hh, b_ih, b_hh, img, S, out);
}

// Round 2
// 406.350 us; speedup vs baseline: 1.1252x; 1.1252x over previous
//
#include <hip/hip_runtime.h>

// SCF GRU layer: T=40 steps, B=128 batches, N=64 agents/batch, H=48 hidden.
// BN = 8192 rows. DIN = 52 = loc(2) + rel(2) + vel(16) + img_feat(32).
//
// Decomposition (2 launches):
//  k_pre : blocks [0,4096)    -> img_feat[b][c] = mean over 80x80 of f_img (HBM-bound, 105 MB)
//          blocks [4096,5376) -> S[t][b][2] = sum of locs over the 64 agents (4 (t,b) per block)
//  k_gru : per-row independent 40-step recurrence. 96 threads/row:
//          thread = (gate j in [0,48), half in {0,1} of K-range).
//          Weights (102 floats/thread) are PINNED into VGPRs with empty inline-asm:
//          at the default 84-VGPR budget the allocator re-loads them from global
//          inside the t-loop (dur 288us, ~300 issued ops/wave-step vs ~130 needed).
//          Pinning forces register residency; __launch_bounds__(192,3) caps at ~168.
//          h and x double-buffered in LDS -> ONE barrier per step.
//          Global loads for step t+1 prefetched into registers before the barrier.

#define T_STEPS 40
#define BB      128
#define NN      64
#define HH      48
#define BN      8192
#define G3      144   // 3*H

#define KEEP1(x) asm volatile("" : "+v"(x))
#define KEEP2(v) do { KEEP1((v).x); KEEP1((v).y); } while (0)

__device__ __forceinline__ float sigmoid_(float x) {
    return __builtin_amdgcn_rcpf(1.0f + __expf(-x));
}

__global__ __launch_bounds__(256) void k_pre(const float* __restrict__ f_img,
                                             const float* __restrict__ path,
                                             float* __restrict__ img_out,
                                             float* __restrict__ S) {
    if (blockIdx.x < 4096) {
        // ---- per-(b,c) image mean over 80x80 = 1600 float4 ----
        const int bc = blockIdx.x;
        const float4* p = reinterpret_cast<const float4*>(f_img + (size_t)bc * 6400);
        float s = 0.0f;
        for (int i = threadIdx.x; i < 1600; i += 256) {
            float4 v = p[i];
            s += v.x + v.y + v.z + v.w;
        }
        for (int off = 32; off > 0; off >>= 1) s += __shfl_down(s, off, 64);
        __shared__ float red[4];
        const int wid = threadIdx.x >> 6, lane = threadIdx.x & 63;
        if (lane == 0) red[wid] = s;
        __syncthreads();
        if (threadIdx.x == 0)
            img_out[bc] = (red[0] + red[1] + red[2] + red[3]) * (1.0f / 6400.0f);
    } else {
        // ---- loc sums: one (t,b) per wave, 4 waves/block ----
        const int tb   = (blockIdx.x - 4096) * 4 + (threadIdx.x >> 6);  // t*128 + b
        const int lane = threadIdx.x & 63;
        const float2 v = reinterpret_cast<const float2*>(path)[(size_t)tb * 64 + lane];
        float sx = v.x, sy = v.y;
        for (int off = 32; off > 0; off >>= 1) {
            sx += __shfl_down(sx, off, 64);
            sy += __shfl_down(sy, off, 64);
        }
        if (lane == 0) {
            float2 o; o.x = sx; o.y = sy;
            reinterpret_cast<float2*>(S)[tb] = o;
        }
    }
}

// Main recurrence. Block = 192 threads = 2 rows x 96 threads.
// Within a row: lane q = j*2 + half, so shfl_xor(1) pairs the two K-halves.
__global__ __launch_bounds__(192, 3) void k_gru(const float* __restrict__ path,
                                                const float* __restrict__ f_vel,
                                                const float* __restrict__ W_ih,
                                                const float* __restrict__ W_hh,
                                                const float* __restrict__ b_ih,
                                                const float* __restrict__ b_hh,
                                                const float* __restrict__ img,
                                                const float* __restrict__ S,
                                                float* __restrict__ out) {
    const int tid  = threadIdx.x;
    const int r    = tid / 96;       // row slot within block
    const int q    = tid % 96;
    const int j    = q >> 1;         // gate/hidden index 0..47
    const int half = q & 1;          // K-range half
    const int row  = blockIdx.x * 2 + r;
    const int b    = row >> 6;       // batch = row / 64  (both rows same batch)

    __shared__ float sh[2][2][HH];   // [buf][row][j]  hidden state, double-buffered
    __shared__ float sx[2][2][20];   // [buf][row][.]  time-varying input, double-buffered
    __shared__ float g0sh[G3];       // per-batch time-invariant gi part

    // ---- G0 prologue: g0[g] = b_ih[g] + img_feat[b] . W_ih[g, 20:52] ----
    if (tid < G3) {
        float acc = b_ih[tid];
        const float* w  = W_ih + tid * 52 + 20;
        const float* im = img + b * 32;
#pragma unroll
        for (int c = 0; c < 32; ++c) acc = fmaf(im[c], w[c], acc);
        g0sh[tid] = acc;
    }

    // ---- weights into registers (float2 pairs) ----
    float2 wihr[5], wihz[5], wihn[5];      // x-part, K-half = 10 floats each gate
    float2 whhr[12], whhz[12], whhn[12];   // h-part, K-half = 24 floats each gate
    {
        const float2* wr = reinterpret_cast<const float2*>(W_ih + (j)      * 52 + half * 10);
        const float2* wz = reinterpret_cast<const float2*>(W_ih + (48 + j) * 52 + half * 10);
        const float2* wn = reinterpret_cast<const float2*>(W_ih + (96 + j) * 52 + half * 10);
#pragma unroll
        for (int p = 0; p < 5; ++p) { wihr[p] = wr[p]; wihz[p] = wz[p]; wihn[p] = wn[p]; }
    }
    {
        const float2* wr = reinterpret_cast<const float2*>(W_hh + (j)      * 48 + half * 24);
        const float2* wz = reinterpret_cast<const float2*>(W_hh + (48 + j) * 48 + half * 24);
        const float2* wn = reinterpret_cast<const float2*>(W_hh + (96 + j) * 48 + half * 24);
#pragma unroll
        for (int p = 0; p < 12; ++p) { whhr[p] = wr[p]; whhz[p] = wz[p]; whhn[p] = wn[p]; }
    }
    // ---- PIN the weights into VGPRs: forbid in-loop re-load/remat ----
#pragma unroll
    for (int p = 0; p < 5; ++p) { KEEP2(wihr[p]); KEEP2(wihz[p]); KEEP2(wihn[p]); }
#pragma unroll
    for (int p = 0; p < 12; ++p) { KEEP2(whhr[p]); KEEP2(whhz[p]); KEEP2(whhn[p]); }

    float bhn = b_hh[96 + j];
    const float bhr = b_hh[j], bhz = b_hh[48 + j];

    if (half == 0) sh[0][r][j] = 0.0f;   // h0 = 0

    // ---- prefetch step-0 inputs into registers ----
    float  vcur = 0.0f, vnxt = 0.0f;
    float2 lcur = {0.f, 0.f}, lnxt = {0.f, 0.f};
    float2 scur = {0.f, 0.f}, snxt = {0.f, 0.f};
    if (q < 16) {
        vcur = f_vel[(size_t)row * 16 + q];
    } else if (q == 16) {
        lcur = reinterpret_cast<const float2*>(path)[row];
        scur = reinterpret_cast<const float2*>(S)[b];
    }

    __syncthreads();   // g0sh + sh[0] ready
    // fold b_hh r/z into the per-thread gate constants (saves 2 adds/step)
    float cr  = g0sh[j]      + bhr;
    float cz  = g0sh[48 + j] + bhz;
    float g0n = g0sh[96 + j];
    KEEP1(cr); KEEP1(cz); KEEP1(g0n); KEEP1(bhn);

    float hp = 0.0f;   // h_prev for this j, carried in a register (both halves identical)
    int p = 0;
    for (int t = 0; t < T_STEPS; ++t) {
        // ---- stage x[t] (held in regs) into LDS buffer p ----
        if (q < 16) {
            sx[p][r][4 + q] = vcur;
        } else if (q == 16) {
            sx[p][r][0] = lcur.x;
            sx[p][r][1] = lcur.y;
            sx[p][r][2] = (scur.x - 64.0f * lcur.x) * (1.0f / 63.0f);  // rel = (S-64*loc)/63
            sx[p][r][3] = (scur.y - 64.0f * lcur.y) * (1.0f / 63.0f);
        }
        // ---- prefetch t+1 (latency hides under this step's compute) ----
        if (t + 1 < T_STEPS) {
            if (q < 16) {
                vnxt = f_vel[((size_t)(t + 1) * BN + row) * 16 + q];
            } else if (q == 16) {
                lnxt = reinterpret_cast<const float2*>(path)[(size_t)(t + 1) * BN + row];
                snxt = reinterpret_cast<const float2*>(S)[(t + 1) * BB + b];
            }
        }
        __syncthreads();   // sx[p] staged, sh[p] (written last step) visible

        const float2* sx2 = reinterpret_cast<const float2*>(sx[p][r]);
        const float2* sh2 = reinterpret_cast<const float2*>(sh[p][r]);

        float2 ar  = {0.0f, 0.0f};   // r-gate: i + h combined
        float2 az  = {0.0f, 0.0f};   // z-gate: i + h combined
        float2 ani = {0.0f, 0.0f};   // n-gate input part
        float2 anh = {0.0f, 0.0f};   // n-gate hidden part (r multiplies this)
#pragma unroll
        for (int pp = 0; pp < 5; ++pp) {
            const float2 xv = sx2[half * 5 + pp];
            ar.x  = fmaf(xv.x, wihr[pp].x, ar.x);  ar.y  = fmaf(xv.y, wihr[pp].y, ar.y);
            az.x  = fmaf(xv.x, wihz[pp].x, az.x);  az.y  = fmaf(xv.y, wihz[pp].y, az.y);
            ani.x = fmaf(xv.x, wihn[pp].x, ani.x); ani.y = fmaf(xv.y, wihn[pp].y, ani.y);
        }
#pragma unroll
        for (int pp = 0; pp < 12; ++pp) {
            const float2 hv = sh2[half * 12 + pp];
            ar.x  = fmaf(hv.x, whhr[pp].x, ar.x);  ar.y  = fmaf(hv.y, whhr[pp].y, ar.y);
            az.x  = fmaf(hv.x, whhz[pp].x, az.x);  az.y  = fmaf(hv.y, whhz[pp].y, az.y);
            anh.x = fmaf(hv.x, whhn[pp].x, anh.x); anh.y = fmaf(hv.y, whhn[pp].y, anh.y);
        }
        float sr  = ar.x + ar.y;   sr  += __shfl_xor(sr, 1, 64);
        float szv = az.x + az.y;   szv += __shfl_xor(szv, 1, 64);
        float sni = ani.x + ani.y; sni += __shfl_xor(sni, 1, 64);
        float snh = anh.x + anh.y; snh += __shfl_xor(snh, 1, 64);

        const float rg = sigmoid_(sr + cr);
        const float zg = sigmoid_(szv + cz);
        float a = (sni + g0n) + rg * (snh + bhn);   // b_hh inside r*h_n (not folded into G0)
        a = fminf(fmaxf(a, -15.0f), 15.0f);
        const float e = __expf(-2.0f * a);
        const float cand = (1.0f - e) * __builtin_amdgcn_rcpf(1.0f + e);
        const float hn = zg * (hp - cand) + cand;   // (1-z)*cand + z*h

        // write to the OTHER buffer -> no pre-write barrier needed
        if (half == 0) {
            sh[p ^ 1][r][j] = hn;
        } else {
            out[((size_t)t * BN + row) * HH + j] = hn;
            if (t == T_STEPS - 1)
                out[(size_t)T_STEPS * BN * HH + (size_t)row * HH + j] = hn;  // hT
        }
        hp = hn;
        vcur = vnxt; lcur = lnxt; scur = snxt;
        p ^= 1;
    }
}

extern "C" void kernel_launch(void* const* d_in, const int* in_sizes, int n_in,
                              void* d_out, int out_size, void* d_ws, size_t ws_size,
                              hipStream_t stream) {
    const float* path  = (const float*)d_in[0];
    const float* f_vel = (const float*)d_in[1];
    const float* f_img = (const float*)d_in[2];
    const float* W_ih  = (const float*)d_in[3];
    const float* W_hh  = (const float*)d_in[4];
    const float* b_ih  = (const float*)d_in[5];
    const float* b_hh  = (const float*)d_in[6];
    float* out = (float*)d_out;

    float* ws  = (float*)d_ws;
    float* img = ws;                  // 4096 floats
    float* S   = ws + 4096;           // 10240 floats (float2-aligned: 16 KB offset)

    // img_mean blocks [0,4096) + ssum blocks [4096, 4096+1280)
    hipLaunchKernelGGL(k_pre, dim3(4096 + (T_STEPS * BB) / 4), dim3(256), 0, stream,
                       f_img, path, img, S);
    hipLaunchKernelGGL(k_gru, dim3(BN / 2), dim3(192), 0, stream,
                       path, f_vel, W_ih, W_hh, b_ih, b_hh, img, S, out);
}

// Round 3
// 405.756 us; speedup vs baseline: 1.1269x; 1.0015x over previous
//
#include <hip/hip_runtime.h>

// SCF GRU layer: T=40 steps, B=128 batches, N=64 agents/batch, H=48 hidden.
// BN = 8192 rows. DIN = 52 = loc(2) + rel(2) + vel(16) + img_feat(32).
//
// Decomposition (2 launches):
//  k_pre : blocks [0,4096)    -> img_feat[b][c] = mean over 80x80 of f_img (HBM-bound, 105 MB)
//          blocks [4096,5376) -> S[t][b][2] = sum of locs over the 64 agents (4 (t,b) per block)
//  k_gru : per-row independent 40-step recurrence. 96 threads/row:
//          thread = (gate j in [0,48), half in {0,1} of K-range).
//          Weights (102 floats/thread) must be VGPR-resident across the t-loop.
//          History: default budget (84 VGPR, ~6 waves/EU target) -> in-loop global
//          reloads (288us). Pins alone -> spill/reload from scratch, still 84 VGPR
//          (238us). Fix: amdgpu_waves_per_eu(3,3) pins target occupancy to 3
//          waves/EU -> register budget ~168, weights stay live, no spills.
//          h and x double-buffered in LDS -> ONE barrier per step.
//          Global loads for step t+1 prefetched into registers before the barrier.

#define T_STEPS 40
#define BB      128
#define NN      64
#define HH      48
#define BN      8192
#define G3      144   // 3*H

#define KEEP1(x) asm volatile("" : "+v"(x))
#define KEEP2(v) do { KEEP1((v).x); KEEP1((v).y); } while (0)

__device__ __forceinline__ float sigmoid_(float x) {
    return __builtin_amdgcn_rcpf(1.0f + __expf(-x));
}

__global__ __launch_bounds__(256) void k_pre(const float* __restrict__ f_img,
                                             const float* __restrict__ path,
                                             float* __restrict__ img_out,
                                             float* __restrict__ S) {
    if (blockIdx.x < 4096) {
        // ---- per-(b,c) image mean over 80x80 = 1600 float4 ----
        const int bc = blockIdx.x;
        const float4* p = reinterpret_cast<const float4*>(f_img + (size_t)bc * 6400);
        float s = 0.0f;
        for (int i = threadIdx.x; i < 1600; i += 256) {
            float4 v = p[i];
            s += v.x + v.y + v.z + v.w;
        }
        for (int off = 32; off > 0; off >>= 1) s += __shfl_down(s, off, 64);
        __shared__ float red[4];
        const int wid = threadIdx.x >> 6, lane = threadIdx.x & 63;
        if (lane == 0) red[wid] = s;
        __syncthreads();
        if (threadIdx.x == 0)
            img_out[bc] = (red[0] + red[1] + red[2] + red[3]) * (1.0f / 6400.0f);
    } else {
        // ---- loc sums: one (t,b) per wave, 4 waves/block ----
        const int tb   = (blockIdx.x - 4096) * 4 + (threadIdx.x >> 6);  // t*128 + b
        const int lane = threadIdx.x & 63;
        const float2 v = reinterpret_cast<const float2*>(path)[(size_t)tb * 64 + lane];
        float sx = v.x, sy = v.y;
        for (int off = 32; off > 0; off >>= 1) {
            sx += __shfl_down(sx, off, 64);
            sy += __shfl_down(sy, off, 64);
        }
        if (lane == 0) {
            float2 o; o.x = sx; o.y = sy;
            reinterpret_cast<float2*>(S)[tb] = o;
        }
    }
}

// Main recurrence. Block = 192 threads = 2 rows x 96 threads.
// Within a row: lane q = j*2 + half, so shfl_xor(1) pairs the two K-halves.
// amdgpu_waves_per_eu(3,3): register budget 512/3 ~= 168 VGPR so the 102
// pinned weight floats stay live across the t-loop (no scratch spill).
__global__ __attribute__((amdgpu_waves_per_eu(3, 3)))
__launch_bounds__(192) void k_gru(const float* __restrict__ path,
                                  const float* __restrict__ f_vel,
                                  const float* __restrict__ W_ih,
                                  const float* __restrict__ W_hh,
                                  const float* __restrict__ b_ih,
                                  const float* __restrict__ b_hh,
                                  const float* __restrict__ img,
                                  const float* __restrict__ S,
                                  float* __restrict__ out) {
    const int tid  = threadIdx.x;
    const int r    = tid / 96;       // row slot within block
    const int q    = tid % 96;
    const int j    = q >> 1;         // gate/hidden index 0..47
    const int half = q & 1;          // K-range half
    const int row  = blockIdx.x * 2 + r;
    const int b    = row >> 6;       // batch = row / 64  (both rows same batch)

    __shared__ float sh[2][2][HH];   // [buf][row][j]  hidden state, double-buffered
    __shared__ float sx[2][2][20];   // [buf][row][.]  time-varying input, double-buffered
    __shared__ float g0sh[G3];       // per-batch time-invariant gi part

    // ---- G0 prologue: g0[g] = b_ih[g] + img_feat[b] . W_ih[g, 20:52] ----
    if (tid < G3) {
        float acc = b_ih[tid];
        const float* w  = W_ih + tid * 52 + 20;
        const float* im = img + b * 32;
#pragma unroll
        for (int c = 0; c < 32; ++c) acc = fmaf(im[c], w[c], acc);
        g0sh[tid] = acc;
    }

    // ---- weights into registers (float2 pairs) ----
    float2 wihr[5], wihz[5], wihn[5];      // x-part, K-half = 10 floats each gate
    float2 whhr[12], whhz[12], whhn[12];   // h-part, K-half = 24 floats each gate
    {
        const float2* wr = reinterpret_cast<const float2*>(W_ih + (j)      * 52 + half * 10);
        const float2* wz = reinterpret_cast<const float2*>(W_ih + (48 + j) * 52 + half * 10);
        const float2* wn = reinterpret_cast<const float2*>(W_ih + (96 + j) * 52 + half * 10);
#pragma unroll
        for (int p = 0; p < 5; ++p) { wihr[p] = wr[p]; wihz[p] = wz[p]; wihn[p] = wn[p]; }
    }
    {
        const float2* wr = reinterpret_cast<const float2*>(W_hh + (j)      * 48 + half * 24);
        const float2* wz = reinterpret_cast<const float2*>(W_hh + (48 + j) * 48 + half * 24);
        const float2* wn = reinterpret_cast<const float2*>(W_hh + (96 + j) * 48 + half * 24);
#pragma unroll
        for (int p = 0; p < 12; ++p) { whhr[p] = wr[p]; whhz[p] = wz[p]; whhn[p] = wn[p]; }
    }
    // ---- PIN the weights into VGPRs: forbid in-loop re-load/remat ----
#pragma unroll
    for (int p = 0; p < 5; ++p) { KEEP2(wihr[p]); KEEP2(wihz[p]); KEEP2(wihn[p]); }
#pragma unroll
    for (int p = 0; p < 12; ++p) { KEEP2(whhr[p]); KEEP2(whhz[p]); KEEP2(whhn[p]); }

    float bhn = b_hh[96 + j];
    const float bhr = b_hh[j], bhz = b_hh[48 + j];

    if (half == 0) sh[0][r][j] = 0.0f;   // h0 = 0

    // ---- prefetch step-0 inputs into registers ----
    float  vcur = 0.0f, vnxt = 0.0f;
    float2 lcur = {0.f, 0.f}, lnxt = {0.f, 0.f};
    float2 scur = {0.f, 0.f}, snxt = {0.f, 0.f};
    if (q < 16) {
        vcur = f_vel[(size_t)row * 16 + q];
    } else if (q == 16) {
        lcur = reinterpret_cast<const float2*>(path)[row];
        scur = reinterpret_cast<const float2*>(S)[b];
    }

    __syncthreads();   // g0sh + sh[0] ready
    // fold b_hh r/z into the per-thread gate constants (saves 2 adds/step)
    float cr  = g0sh[j]      + bhr;
    float cz  = g0sh[48 + j] + bhz;
    float g0n = g0sh[96 + j];
    KEEP1(cr); KEEP1(cz); KEEP1(g0n); KEEP1(bhn);

    float hp = 0.0f;   // h_prev for this j, carried in a register (both halves identical)
    int p = 0;
    for (int t = 0; t < T_STEPS; ++t) {
        // ---- stage x[t] (held in regs) into LDS buffer p ----
        if (q < 16) {
            sx[p][r][4 + q] = vcur;
        } else if (q == 16) {
            sx[p][r][0] = lcur.x;
            sx[p][r][1] = lcur.y;
            sx[p][r][2] = (scur.x - 64.0f * lcur.x) * (1.0f / 63.0f);  // rel = (S-64*loc)/63
            sx[p][r][3] = (scur.y - 64.0f * lcur.y) * (1.0f / 63.0f);
        }
        // ---- prefetch t+1 (latency hides under this step's compute) ----
        if (t + 1 < T_STEPS) {
            if (q < 16) {
                vnxt = f_vel[((size_t)(t + 1) * BN + row) * 16 + q];
            } else if (q == 16) {
                lnxt = reinterpret_cast<const float2*>(path)[(size_t)(t + 1) * BN + row];
                snxt = reinterpret_cast<const float2*>(S)[(t + 1) * BB + b];
            }
        }
        __syncthreads();   // sx[p] staged, sh[p] (written last step) visible

        const float2* sx2 = reinterpret_cast<const float2*>(sx[p][r]);
        const float2* sh2 = reinterpret_cast<const float2*>(sh[p][r]);

        float2 ar  = {0.0f, 0.0f};   // r-gate: i + h combined
        float2 az  = {0.0f, 0.0f};   // z-gate: i + h combined
        float2 ani = {0.0f, 0.0f};   // n-gate input part
        float2 anh = {0.0f, 0.0f};   // n-gate hidden part (r multiplies this)
#pragma unroll
        for (int pp = 0; pp < 5; ++pp) {
            const float2 xv = sx2[half * 5 + pp];
            ar.x  = fmaf(xv.x, wihr[pp].x, ar.x);  ar.y  = fmaf(xv.y, wihr[pp].y, ar.y);
            az.x  = fmaf(xv.x, wihz[pp].x, az.x);  az.y  = fmaf(xv.y, wihz[pp].y, az.y);
            ani.x = fmaf(xv.x, wihn[pp].x, ani.x); ani.y = fmaf(xv.y, wihn[pp].y, ani.y);
        }
#pragma unroll
        for (int pp = 0; pp < 12; ++pp) {
            const float2 hv = sh2[half * 12 + pp];
            ar.x  = fmaf(hv.x, whhr[pp].x, ar.x);  ar.y  = fmaf(hv.y, whhr[pp].y, ar.y);
            az.x  = fmaf(hv.x, whhz[pp].x, az.x);  az.y  = fmaf(hv.y, whhz[pp].y, az.y);
            anh.x = fmaf(hv.x, whhn[pp].x, anh.x); anh.y = fmaf(hv.y, whhn[pp].y, anh.y);
        }
        float sr  = ar.x + ar.y;   sr  += __shfl_xor(sr, 1, 64);
        float szv = az.x + az.y;   szv += __shfl_xor(szv, 1, 64);
        float sni = ani.x + ani.y; sni += __shfl_xor(sni, 1, 64);
        float snh = anh.x + anh.y; snh += __shfl_xor(snh, 1, 64);

        const float rg = sigmoid_(sr + cr);
        const float zg = sigmoid_(szv + cz);
        float a = (sni + g0n) + rg * (snh + bhn);   // b_hh inside r*h_n (not folded into G0)
        a = fminf(fmaxf(a, -15.0f), 15.0f);
        const float e = __expf(-2.0f * a);
        const float cand = (1.0f - e) * __builtin_amdgcn_rcpf(1.0f + e);
        const float hn = zg * (hp - cand) + cand;   // (1-z)*cand + z*h

        // write to the OTHER buffer -> no pre-write barrier needed
        if (half == 0) {
            sh[p ^ 1][r][j] = hn;
        } else {
            out[((size_t)t * BN + row) * HH + j] = hn;
            if (t == T_STEPS - 1)
                out[(size_t)T_STEPS * BN * HH + (size_t)row * HH + j] = hn;  // hT
        }
        hp = hn;
        vcur = vnxt; lcur = lnxt; scur = snxt;
        p ^= 1;
    }
}

extern "C" void kernel_launch(void* const* d_in, const int* in_sizes, int n_in,
                              void* d_out, int out_size, void* d_ws, size_t ws_size,
                              hipStream_t stream) {
    const float* path  = (const float*)d_in[0];
    const float* f_vel = (const float*)d_in[1];
    const float* f_img = (const float*)d_in[2];
    const float* W_ih  = (const float*)d_in[3];
    const float* W_hh  = (const float*)d_in[4];
    const float* b_ih  = (const float*)d_in[5];
    const float* b_hh  = (const float*)d_in[6];
    float* out = (float*)d_out;

    float* ws  = (float*)d_ws;
    float* img = ws;                  // 4096 floats
    float* S   = ws + 4096;           // 10240 floats (float2-aligned: 16 KB offset)

    // img_mean blocks [0,4096) + ssum blocks [4096, 4096+1280)
    hipLaunchKernelGGL(k_pre, dim3(4096 + (T_STEPS * BB) / 4), dim3(256), 0, stream,
                       f_img, path, img, S);
    hipLaunchKernelGGL(k_gru, dim3(BN / 2), dim3(192), 0, stream,
                       path, f_vel, W_ih, W_hh, b_ih, b_hh, img, S, out);
}